// Round 8
// baseline (68.869 us; speedup 1.0000x reference)
//
#include <hip/hip_runtime.h>

#define T_STEPS 100
#define BATCH 256
#define NIN 784
#define N0 64
#define N1 64
#define N2 10
#define CHUNK (BATCH*N0 + BATCH*N1 + BATCH*N2)   // 35328
#define NSPLIT 4
#define PLANE (BATCH*T_STEPS*64)                 // partial plane (floats), b-major [b][t][j]
#define KPAD 800
#define WPLANE (N0*KPAD)                         // 51200 shorts per W0 split plane

typedef __attribute__((ext_vector_type(8))) short short8;
typedef __attribute__((ext_vector_type(4))) float f32x4;

__device__ inline short bf16_rne(float x) {
  unsigned u = __float_as_uint(x);
  unsigned h = (u + 0x7FFFu + ((u >> 16) & 1u)) >> 16;
  return (short)h;
}
__device__ inline float bf16_val(short h) {
  return __uint_as_float(((unsigned)(unsigned short)h) << 16);
}

// ---------------------------------------------------------------------------
// Kernel 0: split W0 (f32 [64][784]) into 3 bf16 planes [64][800] (zero-pad).
// ---------------------------------------------------------------------------
__global__ __launch_bounds__(256) void prep_w0(
    const float* __restrict__ W0, short* __restrict__ W0s) {
  int idx = blockIdx.x * 256 + threadIdx.x;      // 0..51199
  int col = idx / KPAD, k = idx - col * KPAD;
  float w = (k < NIN) ? W0[col * NIN + k] : 0.0f;
  short h0 = bf16_rne(w);
  float r1 = w - bf16_val(h0);
  short h1 = bf16_rne(r1);
  float r2 = r1 - bf16_val(h1);
  short h2 = bf16_rne(r2);
  W0s[idx]              = h0;
  W0s[WPLANE + idx]     = h1;
  W0s[2 * WPLANE + idx] = h2;
}

// ---------------------------------------------------------------------------
// Kernel 1: partial I0 = X @ W0^T via bf16x3 MFMA (6 products).
// Tile 64 rows x 64 cols, 256 threads (4 waves, each 32x32 = 2x2 MFMA tiles).
// K-split over blockIdx.y: splits {192,192,192,208+pad16}. Chunk BK=32.
// Output b-major P[s][b][t][j]. LDS 30.7 KB, single-buffer, reg-prefetch.
// ---------------------------------------------------------------------------
__global__ __launch_bounds__(256) void gemm0_kernel(
    const float* __restrict__ X, const short* __restrict__ W0s,
    float* __restrict__ P) {
  __shared__ __align__(16) short Al[3][64][40];  // [split][row][k 32 bf16 + pad]
  __shared__ __align__(16) short Bl[3][64][40];  // [split][col][k]

  const int tid = threadIdx.x;
  const int r0  = blockIdx.x * 64;
  const int s   = blockIdx.y;
  const int kbeg = s * 192;
  const int ccnt = (s < 3) ? 6 : 7;              // last split: 208 real k + 16 zero-pad

  // staging maps
  const int srow = tid >> 2;                     // 0..63 (A row / B col)
  const int skq  = tid & 3;                      // k-oct

  // MFMA lane maps
  const int w  = tid >> 6;                       // wave 0..3
  const int l  = tid & 63;
  const int lr = l & 15;                         // frag row/col
  const int lk = l >> 4;                         // frag k-oct
  const int rtb = (w >> 1) * 2;                  // row-tile base (16-row units)
  const int ctb = (w & 1) * 2;                   // col-tile base

  f32x4 zz = {0.0f, 0.0f, 0.0f, 0.0f};
  f32x4 acc[2][2];
  acc[0][0] = zz; acc[0][1] = zz; acc[1][0] = zz; acc[1][1] = zz;

  const float* xrow = X + (size_t)(r0 + srow) * NIN;
  const float4 zero4 = {0.0f, 0.0f, 0.0f, 0.0f};

  // ---- prologue: stage chunk 0
  {
    const int kb = kbeg;
    const int k0 = kb + skq * 8;
    float4 xa = (k0     < NIN) ? *(const float4*)(xrow + k0)     : zero4;
    float4 xb = (k0 + 4 < NIN) ? *(const float4*)(xrow + k0 + 4) : zero4;
    short8 wv0 = *(const short8*)(W0s +              (size_t)srow * KPAD + kb + skq * 8);
    short8 wv1 = *(const short8*)(W0s + WPLANE +     (size_t)srow * KPAD + kb + skq * 8);
    short8 wv2 = *(const short8*)(W0s + 2 * WPLANE + (size_t)srow * KPAD + kb + skq * 8);
    float xs[8] = {xa.x, xa.y, xa.z, xa.w, xb.x, xb.y, xb.z, xb.w};
    short8 v0, v1, v2;
#pragma unroll
    for (int e = 0; e < 8; ++e) {
      float x = xs[e];
      short h0 = bf16_rne(x);
      float rr1 = x - bf16_val(h0);
      short h1 = bf16_rne(rr1);
      float rr2 = rr1 - bf16_val(h1);
      short h2 = bf16_rne(rr2);
      v0[e] = h0; v1[e] = h1; v2[e] = h2;
    }
    *(short8*)&Al[0][srow][skq * 8] = v0;
    *(short8*)&Al[1][srow][skq * 8] = v1;
    *(short8*)&Al[2][srow][skq * 8] = v2;
    *(short8*)&Bl[0][srow][skq * 8] = wv0;
    *(short8*)&Bl[1][srow][skq * 8] = wv1;
    *(short8*)&Bl[2][srow][skq * 8] = wv2;
  }
  __syncthreads();

  for (int c = 0; c < ccnt; ++c) {
    const bool more = (c + 1 < ccnt);
    // ---- prefetch next chunk into registers (latency hides under MFMAs)
    float4 xa, xb;
    short8 wv0, wv1, wv2;
    if (more) {
      const int kb = kbeg + (c + 1) * 32;
      const int k0 = kb + skq * 8;
      xa = (k0     < NIN) ? *(const float4*)(xrow + k0)     : zero4;
      xb = (k0 + 4 < NIN) ? *(const float4*)(xrow + k0 + 4) : zero4;
      wv0 = *(const short8*)(W0s +              (size_t)srow * KPAD + kb + skq * 8);
      wv1 = *(const short8*)(W0s + WPLANE +     (size_t)srow * KPAD + kb + skq * 8);
      wv2 = *(const short8*)(W0s + 2 * WPLANE + (size_t)srow * KPAD + kb + skq * 8);
    }

    // ---- compute this chunk: 2x2 tiles x 6 bf16x3 products
    short8 af[2][3];
#pragma unroll
    for (int rti = 0; rti < 2; ++rti)
#pragma unroll
      for (int p = 0; p < 3; ++p)
        af[rti][p] = *(const short8*)&Al[p][(rtb + rti) * 16 + lr][lk * 8];

#pragma unroll
    for (int cti = 0; cti < 2; ++cti) {
      short8 bf0 = *(const short8*)&Bl[0][(ctb + cti) * 16 + lr][lk * 8];
      short8 bf1 = *(const short8*)&Bl[1][(ctb + cti) * 16 + lr][lk * 8];
      short8 bf2 = *(const short8*)&Bl[2][(ctb + cti) * 16 + lr][lk * 8];
#pragma unroll
      for (int rti = 0; rti < 2; ++rti) {
        f32x4 a = acc[rti][cti];
        a = __builtin_amdgcn_mfma_f32_16x16x32_bf16(af[rti][2], bf0, a, 0, 0, 0);
        a = __builtin_amdgcn_mfma_f32_16x16x32_bf16(af[rti][0], bf2, a, 0, 0, 0);
        a = __builtin_amdgcn_mfma_f32_16x16x32_bf16(af[rti][1], bf1, a, 0, 0, 0);
        a = __builtin_amdgcn_mfma_f32_16x16x32_bf16(af[rti][1], bf0, a, 0, 0, 0);
        a = __builtin_amdgcn_mfma_f32_16x16x32_bf16(af[rti][0], bf1, a, 0, 0, 0);
        a = __builtin_amdgcn_mfma_f32_16x16x32_bf16(af[rti][0], bf0, a, 0, 0, 0);
        acc[rti][cti] = a;
      }
    }

    if (more) {
      __syncthreads();               // all reads of current chunk done
      float xs[8] = {xa.x, xa.y, xa.z, xa.w, xb.x, xb.y, xb.z, xb.w};
      short8 v0, v1, v2;
#pragma unroll
      for (int e = 0; e < 8; ++e) {
        float x = xs[e];
        short h0 = bf16_rne(x);
        float rr1 = x - bf16_val(h0);
        short h1 = bf16_rne(rr1);
        float rr2 = rr1 - bf16_val(h1);
        short h2 = bf16_rne(rr2);
        v0[e] = h0; v1[e] = h1; v2[e] = h2;
      }
      *(short8*)&Al[0][srow][skq * 8] = v0;
      *(short8*)&Al[1][srow][skq * 8] = v1;
      *(short8*)&Al[2][srow][skq * 8] = v2;
      *(short8*)&Bl[0][srow][skq * 8] = wv0;
      *(short8*)&Bl[1][srow][skq * 8] = wv1;
      *(short8*)&Bl[2][srow][skq * 8] = wv2;
      __syncthreads();               // next chunk visible
    }
  }

  // ---- epilogue: b-major write. C/D map: col = lane&15, row = (lane>>4)*4+r.
  const int t0  = r0 >> 8;
  const int bb0 = r0 & 255;
  float* op = P + (size_t)s * PLANE;
#pragma unroll
  for (int rti = 0; rti < 2; ++rti)
#pragma unroll
    for (int cti = 0; cti < 2; ++cti)
#pragma unroll
      for (int r = 0; r < 4; ++r) {
        int row = (rtb + rti) * 16 + lk * 4 + r;   // local 0..63
        int j   = (ctb + cti) * 16 + lr;
        op[((size_t)(bb0 + row) * T_STEPS + t0) * 64 + j] = acc[rti][cti][r];
      }
}

// ---------------------------------------------------------------------------
// Kernel 2: one block per batch element (unchanged from R7).
// ---------------------------------------------------------------------------
__global__ __launch_bounds__(256) void fused_kernel(
    const float* __restrict__ P, const float* __restrict__ b0,
    const float* __restrict__ W1, const float* __restrict__ b1,
    const float* __restrict__ W2, const float* __restrict__ b2,
    float* __restrict__ out) {
  __shared__ float bufA[112][68];
  __shared__ float sW1t[64][68];
  __shared__ float sW2[N2][68];
  __shared__ float sI2[T_STEPS][N2];

  const int b   = blockIdx.x;
  const int tid = threadIdx.x;
  const int j   = tid & 63;
  const int tq  = tid >> 6;
  float* outSpk = out;
  float* laySpk = out + T_STEPS * BATCH * N2;

  {
    const float4* base = (const float4*)P + (size_t)b * (T_STEPS * 16);
    const size_t pstep = PLANE / 4;
    for (int idx = tid; idx < T_STEPS * 16; idx += 256) {
      float4 v  = base[idx];
      float4 u1 = base[idx + pstep];
      float4 u2 = base[idx + 2 * pstep];
      float4 u3 = base[idx + 3 * pstep];
      v.x += u1.x; v.y += u1.y; v.z += u1.z; v.w += u1.w;
      v.x += u2.x; v.y += u2.y; v.z += u2.z; v.w += u2.w;
      v.x += u3.x; v.y += u3.y; v.z += u3.z; v.w += u3.w;
      int t = idx >> 4, j4 = idx & 15;
      float4 bv = ((const float4*)b0)[j4];
      v.x += bv.x; v.y += bv.y; v.z += bv.z; v.w += bv.w;
      *(float4*)&bufA[t][j4 * 4] = v;
    }
  }
  __syncthreads();

  if (tq == 0) {
    float v = 0.0f;
#pragma unroll
    for (int g = 0; g < 4; ++g) {
      float ic[25];
#pragma unroll
      for (int i = 0; i < 25; ++i) ic[i] = bufA[g * 25 + i][j];
#pragma unroll
      for (int i = 0; i < 25; ++i) {
        v = v + 0.05f * ((0.0f - v) + ic[i]);
        float z = (v > 1.0f) ? 1.0f : 0.0f;
        v -= z;
        ic[i] = z;
      }
#pragma unroll
      for (int i = 0; i < 25; ++i) bufA[g * 25 + i][j] = ic[i];
    }
  } else {
    for (int idx = tid - 64; idx < 64 * 16; idx += 192) {
      int i = idx >> 4, jv = idx & 15;
      float4 wv = *(const float4*)(W1 + (size_t)i * 64 + jv * 4);
      sW1t[jv * 4 + 0][i] = wv.x;
      sW1t[jv * 4 + 1][i] = wv.y;
      sW1t[jv * 4 + 2][i] = wv.z;
      sW1t[jv * 4 + 3][i] = wv.w;
    }
    for (int idx = tid - 64; idx < N2 * 16; idx += 192) {
      int o = idx >> 4, jv = idx & 15;
      *(float4*)&sW2[o][jv * 4] = *(const float4*)(W2 + (size_t)o * 64 + jv * 4);
    }
  }
  __syncthreads();

  for (int idx = tid; idx < T_STEPS * 16; idx += 256) {
    int t = idx >> 4, jv = idx & 15;
    *(float4*)(laySpk + (size_t)t * CHUNK + b * 64 + jv * 4) =
        *(const float4*)&bufA[t][jv * 4];
  }

  const int iq = tid & 15;
  const int ts = tid >> 4;
  float g1[4][7];
  {
    float4 bias = *(const float4*)(b1 + iq * 4);
#pragma unroll
    for (int tt = 0; tt < 7; ++tt) {
      g1[0][tt] = bias.x; g1[1][tt] = bias.y; g1[2][tt] = bias.z; g1[3][tt] = bias.w;
    }
#pragma unroll
    for (int jq = 0; jq < 16; ++jq) {
      float4 z4[7];
#pragma unroll
      for (int tt = 0; tt < 7; ++tt)
        z4[tt] = *(const float4*)&bufA[ts * 7 + tt][jq * 4];
      float4 w4[4];
#pragma unroll
      for (int e = 0; e < 4; ++e)
        w4[e] = *(const float4*)&sW1t[jq * 4 + e][iq * 4];
#pragma unroll
      for (int e = 0; e < 4; ++e) {
#pragma unroll
        for (int tt = 0; tt < 7; ++tt) {
          float zv = ((const float*)&z4[tt])[e];
          g1[0][tt] = fmaf(zv, w4[e].x, g1[0][tt]);
          g1[1][tt] = fmaf(zv, w4[e].y, g1[1][tt]);
          g1[2][tt] = fmaf(zv, w4[e].z, g1[2][tt]);
          g1[3][tt] = fmaf(zv, w4[e].w, g1[3][tt]);
        }
      }
    }
  }
  __syncthreads();
#pragma unroll
  for (int tt = 0; tt < 7; ++tt) {
    float4 o = {g1[0][tt], g1[1][tt], g1[2][tt], g1[3][tt]};
    *(float4*)&bufA[ts * 7 + tt][iq * 4] = o;
  }
  __syncthreads();

  if (tq == 0) {
    float v = 0.0f;
#pragma unroll
    for (int g = 0; g < 4; ++g) {
      float ic[25];
#pragma unroll
      for (int i = 0; i < 25; ++i) ic[i] = bufA[g * 25 + i][j];
#pragma unroll
      for (int i = 0; i < 25; ++i) {
        v = v + 0.05f * ((0.0f - v) + ic[i]);
        float z = (v > 1.0f) ? 1.0f : 0.0f;
        v -= z;
        ic[i] = z;
      }
#pragma unroll
      for (int i = 0; i < 25; ++i) bufA[g * 25 + i][j] = ic[i];
    }
  }
  __syncthreads();

  for (int idx = tid; idx < T_STEPS * 16; idx += 256) {
    int t = idx >> 4, jv = idx & 15;
    *(float4*)(laySpk + (size_t)t * CHUNK + BATCH * N0 + b * 64 + jv * 4) =
        *(const float4*)&bufA[t][jv * 4];
  }

  for (int idx = tid; idx < T_STEPS * N2; idx += 256) {
    int t = idx / N2, o = idx % N2;
    float a = b2[o];
#pragma unroll
    for (int jq = 0; jq < 16; ++jq) {
      float4 z = *(const float4*)&bufA[t][jq * 4];
      float4 wv = *(const float4*)&sW2[o][jq * 4];
      a += z.x * wv.x;
      a += z.y * wv.y;
      a += z.z * wv.z;
      a += z.w * wv.w;
    }
    sI2[t][o] = a;
  }
  __syncthreads();

  if (tid < N2) {
    float v = 0.0f;
#pragma unroll
    for (int g = 0; g < 4; ++g) {
      float ic[25];
#pragma unroll
      for (int i = 0; i < 25; ++i) ic[i] = sI2[g * 25 + i][tid];
#pragma unroll
      for (int i = 0; i < 25; ++i) {
        v = v + 0.05f * ((0.0f - v) + ic[i]);
        float z = (v > 1.0f) ? 1.0f : 0.0f;
        v -= z;
        ic[i] = z;
      }
#pragma unroll
      for (int i = 0; i < 25; ++i) sI2[g * 25 + i][tid] = ic[i];
    }
  }
  __syncthreads();

  for (int idx = tid; idx < T_STEPS * N2; idx += 256) {
    int t = idx / N2, o = idx % N2;
    float z = sI2[t][o];
    outSpk[(size_t)t * (BATCH * N2) + b * N2 + o] = z;
    laySpk[(size_t)t * CHUNK + BATCH * (N0 + N1) + b * N2 + o] = z;
  }
}

extern "C" void kernel_launch(void* const* d_in, const int* in_sizes, int n_in,
                              void* d_out, int out_size, void* d_ws, size_t ws_size,
                              hipStream_t stream) {
  const float* inp = (const float*)d_in[0];
  const float* W0  = (const float*)d_in[1];
  const float* b0  = (const float*)d_in[2];
  const float* W1  = (const float*)d_in[3];
  const float* b1  = (const float*)d_in[4];
  const float* W2  = (const float*)d_in[5];
  const float* b2  = (const float*)d_in[6];

  float* P   = (float*)d_ws;                          // 4 planes x 6.55 MB
  short* W0s = (short*)(P + (size_t)NSPLIT * PLANE);  // 3 x 100 KB bf16 splits

  prep_w0<<<dim3(200), dim3(256), 0, stream>>>(W0, W0s);
  gemm0_kernel<<<dim3(400, NSPLIT), dim3(256), 0, stream>>>(inp, W0s, P);
  fused_kernel<<<dim3(BATCH), dim3(256), 0, stream>>>(P, b0, W1, b1, W2, b2,
                                                      (float*)d_out);
}

// Round 9
// 62.306 us; speedup vs baseline: 1.1053x; 1.1053x over previous
//
#include <hip/hip_runtime.h>

#define T_STEPS 100
#define BATCH 256
#define NIN 784
#define N0 64
#define N1 64
#define N2 10
#define CHUNK (BATCH*N0 + BATCH*N1 + BATCH*N2)   // 35328
#define KPAD 800
#define WPLANE (N0*KPAD)                         // 51200 shorts per split plane
#define I0ELEMS (25600*64)

typedef __attribute__((ext_vector_type(8))) short short8;
typedef __attribute__((ext_vector_type(4))) float f32x4;

__device__ inline short bf16_rne(float x) {
  unsigned u = __float_as_uint(x);
  unsigned h = (u + 0x7FFFu + ((u >> 16) & 1u)) >> 16;
  return (short)h;
}
__device__ inline float bf16_val(short h) {
  return __uint_as_float(((unsigned)(unsigned short)h) << 16);
}

// ---------------------------------------------------------------------------
// Kernel 0: split W0 (f32 [64][784]) into 3 bf16 planes [64][800] (zero-pad).
// ---------------------------------------------------------------------------
__global__ __launch_bounds__(256) void prep_w0(
    const float* __restrict__ W0, short* __restrict__ W0s) {
  int idx = blockIdx.x * 256 + threadIdx.x;      // 0..51199
  int col = idx / KPAD, k = idx - col * KPAD;
  float w = (k < NIN) ? W0[col * NIN + k] : 0.0f;
  short h0 = bf16_rne(w);
  float r1 = w - bf16_val(h0);
  short h1 = bf16_rne(r1);
  float r2 = r1 - bf16_val(h1);
  short h2 = bf16_rne(r2);
  W0s[idx]              = h0;
  W0s[WPLANE + idx]     = h1;
  W0s[2 * WPLANE + idx] = h2;
}

// ---------------------------------------------------------------------------
// Kernel 1: I0T = X @ W0^T + b0 via bf16x3 MFMA, fragments DIRECT FROM GLOBAL
// (no LDS / no barriers in the k-loop). Block = 32 rows x 64 cols; 4 waves =
// 4 k-ranges {192,192,192,224(pad)} — same ranges/chunk/product order as R8.
// Epilogue: LDS reduce of the 4 wave-partials (+bias, R8 add order), b-major
// write of final I0T. Grid 800.
// ---------------------------------------------------------------------------
__global__ __launch_bounds__(256, 3) void gemm0_kernel(
    const float* __restrict__ X, const short* __restrict__ W0s,
    const float* __restrict__ b0, float* __restrict__ I0T) {
  __shared__ float red[4][32][68];               // 34.8 KB wave-partials

  const int tid = threadIdx.x;
  const int r0  = blockIdx.x * 32;
  const int wid = tid >> 6;                      // wave 0..3 = k-split
  const int l   = tid & 63;
  const int lr  = l & 15;                        // frag row/col lane
  const int lk  = l >> 4;                        // frag k-octet lane

  const int kbeg = wid * 192;
  const int ccnt = (wid < 3) ? 6 : 7;            // last: 208 real k + 16 pad

  f32x4 acc[2][4];                               // [row-tile][col-tile]
#pragma unroll
  for (int rt = 0; rt < 2; ++rt)
#pragma unroll
    for (int ct = 0; ct < 4; ++ct) acc[rt][ct] = f32x4{0.f, 0.f, 0.f, 0.f};

  const float*  xr0 = X + (size_t)(r0 + lr) * NIN;       // row-tile 0 row
  const float*  xr1 = xr0 + 16 * NIN;                    // row-tile 1 row
  const short8* wp  = (const short8*)W0s;                // 100 short8 per row

  for (int c = 0; c < ccnt; ++c) {
    const int kb = kbeg + c * 32;
    const int k0 = kb + lk * 8;

    // ---- A: 8 f32 per row-tile, direct from global (guard only pad tail)
    float4 xa0, xb0, xa1, xb1;
    if (k0 < NIN) {                              // k0 % 8 == 0 -> k0+8 <= 784
      xa0 = *(const float4*)(xr0 + k0);
      xb0 = *(const float4*)(xr0 + k0 + 4);
      xa1 = *(const float4*)(xr1 + k0);
      xb1 = *(const float4*)(xr1 + k0 + 4);
    } else {
      xa0 = xb0 = xa1 = xb1 = float4{0.f, 0.f, 0.f, 0.f};
    }

    // ---- convert to bf16x3 fragments in-register
    short8 a0[3], a1[3];
    {
      float xs0[8] = {xa0.x, xa0.y, xa0.z, xa0.w, xb0.x, xb0.y, xb0.z, xb0.w};
      float xs1[8] = {xa1.x, xa1.y, xa1.z, xa1.w, xb1.x, xb1.y, xb1.z, xb1.w};
#pragma unroll
      for (int e = 0; e < 8; ++e) {
        float x  = xs0[e];
        short h0 = bf16_rne(x);   float rr1 = x - bf16_val(h0);
        short h1 = bf16_rne(rr1); float rr2 = rr1 - bf16_val(h1);
        a0[0][e] = h0; a0[1][e] = h1; a0[2][e] = bf16_rne(rr2);
        x  = xs1[e];
        h0 = bf16_rne(x);   rr1 = x - bf16_val(h0);
        h1 = bf16_rne(rr1); rr2 = rr1 - bf16_val(h1);
        a1[0][e] = h0; a1[1][e] = h1; a1[2][e] = bf16_rne(rr2);
      }
    }

    // ---- B: direct from global (12 KB/chunk shared working set -> L1)
    const int kof = kb / 8 + lk;                 // short8 offset within row
#pragma unroll
    for (int ct = 0; ct < 4; ++ct) {
      const size_t col = (size_t)(ct * 16 + lr);
      short8 bf0 = wp[        col * 100 + kof];
      short8 bf1 = wp[ 6400 + col * 100 + kof];
      short8 bf2 = wp[12800 + col * 100 + kof];
      {
        f32x4 a = acc[0][ct];
        a = __builtin_amdgcn_mfma_f32_16x16x32_bf16(a0[2], bf0, a, 0, 0, 0);
        a = __builtin_amdgcn_mfma_f32_16x16x32_bf16(a0[0], bf2, a, 0, 0, 0);
        a = __builtin_amdgcn_mfma_f32_16x16x32_bf16(a0[1], bf1, a, 0, 0, 0);
        a = __builtin_amdgcn_mfma_f32_16x16x32_bf16(a0[1], bf0, a, 0, 0, 0);
        a = __builtin_amdgcn_mfma_f32_16x16x32_bf16(a0[0], bf1, a, 0, 0, 0);
        a = __builtin_amdgcn_mfma_f32_16x16x32_bf16(a0[0], bf0, a, 0, 0, 0);
        acc[0][ct] = a;
      }
      {
        f32x4 a = acc[1][ct];
        a = __builtin_amdgcn_mfma_f32_16x16x32_bf16(a1[2], bf0, a, 0, 0, 0);
        a = __builtin_amdgcn_mfma_f32_16x16x32_bf16(a1[0], bf2, a, 0, 0, 0);
        a = __builtin_amdgcn_mfma_f32_16x16x32_bf16(a1[1], bf1, a, 0, 0, 0);
        a = __builtin_amdgcn_mfma_f32_16x16x32_bf16(a1[1], bf0, a, 0, 0, 0);
        a = __builtin_amdgcn_mfma_f32_16x16x32_bf16(a1[0], bf1, a, 0, 0, 0);
        a = __builtin_amdgcn_mfma_f32_16x16x32_bf16(a1[0], bf0, a, 0, 0, 0);
        acc[1][ct] = a;
      }
    }
  }

  // ---- epilogue: wave-partials -> LDS  (C/D: col=l&15, row=(l>>4)*4+r)
#pragma unroll
  for (int rt = 0; rt < 2; ++rt)
#pragma unroll
    for (int ct = 0; ct < 4; ++ct)
#pragma unroll
      for (int r = 0; r < 4; ++r)
        red[wid][rt * 16 + lk * 4 + r][ct * 16 + lr] = acc[rt][ct][r];
  __syncthreads();

  // ---- reduce 4 partials + bias (R8 order), write b-major I0T
  const int t0  = r0 >> 8;
  const int bb0 = r0 & 255;
  for (int idx = tid; idx < 32 * 16; idx += 256) {
    int row = idx >> 4, q = idx & 15;
    float4 v  = *(const float4*)&red[0][row][q * 4];
    float4 u1 = *(const float4*)&red[1][row][q * 4];
    float4 u2 = *(const float4*)&red[2][row][q * 4];
    float4 u3 = *(const float4*)&red[3][row][q * 4];
    v.x += u1.x; v.y += u1.y; v.z += u1.z; v.w += u1.w;
    v.x += u2.x; v.y += u2.y; v.z += u2.z; v.w += u2.w;
    v.x += u3.x; v.y += u3.y; v.z += u3.z; v.w += u3.w;
    float4 bv = ((const float4*)b0)[q];
    v.x += bv.x; v.y += bv.y; v.z += bv.z; v.w += bv.w;
    ((float4*)I0T)[((size_t)(bb0 + row) * T_STEPS + t0) * 16 + q] = v;
  }
}

// ---------------------------------------------------------------------------
// Kernel 2: one block per batch element (R7/R8 body; staging reads final I0T
// slab directly — bias already applied).
// ---------------------------------------------------------------------------
__global__ __launch_bounds__(256) void fused_kernel(
    const float* __restrict__ I0T,
    const float* __restrict__ W1, const float* __restrict__ b1,
    const float* __restrict__ W2, const float* __restrict__ b2,
    float* __restrict__ out) {
  __shared__ float bufA[112][68];
  __shared__ float sW1t[64][68];
  __shared__ float sW2[N2][68];
  __shared__ float sI2[T_STEPS][N2];

  const int b   = blockIdx.x;
  const int tid = threadIdx.x;
  const int j   = tid & 63;
  const int tq  = tid >> 6;
  float* outSpk = out;
  float* laySpk = out + T_STEPS * BATCH * N2;

  {
    const float4* src = (const float4*)I0T + (size_t)b * (T_STEPS * 16);
    for (int idx = tid; idx < T_STEPS * 16; idx += 256) {
      float4 v = src[idx];
      int t = idx >> 4, j4 = idx & 15;
      *(float4*)&bufA[t][j4 * 4] = v;
    }
  }
  __syncthreads();

  if (tq == 0) {
    float v = 0.0f;
#pragma unroll
    for (int g = 0; g < 4; ++g) {
      float ic[25];
#pragma unroll
      for (int i = 0; i < 25; ++i) ic[i] = bufA[g * 25 + i][j];
#pragma unroll
      for (int i = 0; i < 25; ++i) {
        v = v + 0.05f * ((0.0f - v) + ic[i]);
        float z = (v > 1.0f) ? 1.0f : 0.0f;
        v -= z;
        ic[i] = z;
      }
#pragma unroll
      for (int i = 0; i < 25; ++i) bufA[g * 25 + i][j] = ic[i];
    }
  } else {
    for (int idx = tid - 64; idx < 64 * 16; idx += 192) {
      int i = idx >> 4, jv = idx & 15;
      float4 wv = *(const float4*)(W1 + (size_t)i * 64 + jv * 4);
      sW1t[jv * 4 + 0][i] = wv.x;
      sW1t[jv * 4 + 1][i] = wv.y;
      sW1t[jv * 4 + 2][i] = wv.z;
      sW1t[jv * 4 + 3][i] = wv.w;
    }
    for (int idx = tid - 64; idx < N2 * 16; idx += 192) {
      int o = idx >> 4, jv = idx & 15;
      *(float4*)&sW2[o][jv * 4] = *(const float4*)(W2 + (size_t)o * 64 + jv * 4);
    }
  }
  __syncthreads();

  for (int idx = tid; idx < T_STEPS * 16; idx += 256) {
    int t = idx >> 4, jv = idx & 15;
    *(float4*)(laySpk + (size_t)t * CHUNK + b * 64 + jv * 4) =
        *(const float4*)&bufA[t][jv * 4];
  }

  const int iq = tid & 15;
  const int ts = tid >> 4;
  float g1[4][7];
  {
    float4 bias = *(const float4*)(b1 + iq * 4);
#pragma unroll
    for (int tt = 0; tt < 7; ++tt) {
      g1[0][tt] = bias.x; g1[1][tt] = bias.y; g1[2][tt] = bias.z; g1[3][tt] = bias.w;
    }
#pragma unroll
    for (int jq = 0; jq < 16; ++jq) {
      float4 z4[7];
#pragma unroll
      for (int tt = 0; tt < 7; ++tt)
        z4[tt] = *(const float4*)&bufA[ts * 7 + tt][jq * 4];
      float4 w4[4];
#pragma unroll
      for (int e = 0; e < 4; ++e)
        w4[e] = *(const float4*)&sW1t[jq * 4 + e][iq * 4];
#pragma unroll
      for (int e = 0; e < 4; ++e) {
#pragma unroll
        for (int tt = 0; tt < 7; ++tt) {
          float zv = ((const float*)&z4[tt])[e];
          g1[0][tt] = fmaf(zv, w4[e].x, g1[0][tt]);
          g1[1][tt] = fmaf(zv, w4[e].y, g1[1][tt]);
          g1[2][tt] = fmaf(zv, w4[e].z, g1[2][tt]);
          g1[3][tt] = fmaf(zv, w4[e].w, g1[3][tt]);
        }
      }
    }
  }
  __syncthreads();
#pragma unroll
  for (int tt = 0; tt < 7; ++tt) {
    float4 o = {g1[0][tt], g1[1][tt], g1[2][tt], g1[3][tt]};
    *(float4*)&bufA[ts * 7 + tt][iq * 4] = o;
  }
  __syncthreads();

  if (tq == 0) {
    float v = 0.0f;
#pragma unroll
    for (int g = 0; g < 4; ++g) {
      float ic[25];
#pragma unroll
      for (int i = 0; i < 25; ++i) ic[i] = bufA[g * 25 + i][j];
#pragma unroll
      for (int i = 0; i < 25; ++i) {
        v = v + 0.05f * ((0.0f - v) + ic[i]);
        float z = (v > 1.0f) ? 1.0f : 0.0f;
        v -= z;
        ic[i] = z;
      }
#pragma unroll
      for (int i = 0; i < 25; ++i) bufA[g * 25 + i][j] = ic[i];
    }
  }
  __syncthreads();

  for (int idx = tid; idx < T_STEPS * 16; idx += 256) {
    int t = idx >> 4, jv = idx & 15;
    *(float4*)(laySpk + (size_t)t * CHUNK + BATCH * N0 + b * 64 + jv * 4) =
        *(const float4*)&bufA[t][jv * 4];
  }

  for (int idx = tid; idx < T_STEPS * N2; idx += 256) {
    int t = idx / N2, o = idx % N2;
    float a = b2[o];
#pragma unroll
    for (int jq = 0; jq < 16; ++jq) {
      float4 z = *(const float4*)&bufA[t][jq * 4];
      float4 wv = *(const float4*)&sW2[o][jq * 4];
      a += z.x * wv.x;
      a += z.y * wv.y;
      a += z.z * wv.z;
      a += z.w * wv.w;
    }
    sI2[t][o] = a;
  }
  __syncthreads();

  if (tid < N2) {
    float v = 0.0f;
#pragma unroll
    for (int g = 0; g < 4; ++g) {
      float ic[25];
#pragma unroll
      for (int i = 0; i < 25; ++i) ic[i] = sI2[g * 25 + i][tid];
#pragma unroll
      for (int i = 0; i < 25; ++i) {
        v = v + 0.05f * ((0.0f - v) + ic[i]);
        float z = (v > 1.0f) ? 1.0f : 0.0f;
        v -= z;
        ic[i] = z;
      }
#pragma unroll
      for (int i = 0; i < 25; ++i) sI2[g * 25 + i][tid] = ic[i];
    }
  }
  __syncthreads();

  for (int idx = tid; idx < T_STEPS * N2; idx += 256) {
    int t = idx / N2, o = idx % N2;
    float z = sI2[t][o];
    outSpk[(size_t)t * (BATCH * N2) + b * N2 + o] = z;
    laySpk[(size_t)t * CHUNK + BATCH * (N0 + N1) + b * N2 + o] = z;
  }
}

extern "C" void kernel_launch(void* const* d_in, const int* in_sizes, int n_in,
                              void* d_out, int out_size, void* d_ws, size_t ws_size,
                              hipStream_t stream) {
  const float* inp = (const float*)d_in[0];
  const float* W0  = (const float*)d_in[1];
  const float* b0  = (const float*)d_in[2];
  const float* W1  = (const float*)d_in[3];
  const float* b1  = (const float*)d_in[4];
  const float* W2  = (const float*)d_in[5];
  const float* b2  = (const float*)d_in[6];

  float* I0T = (float*)d_ws;                 // 6.55 MB, b-major [b][t][j]
  short* W0s = (short*)(I0T + I0ELEMS);      // 3 x 100 KB bf16 splits

  prep_w0<<<dim3(200), dim3(256), 0, stream>>>(W0, W0s);
  gemm0_kernel<<<dim3(800), dim3(256), 0, stream>>>(inp, W0s, b0, I0T);
  fused_kernel<<<dim3(BATCH), dim3(256), 0, stream>>>(I0T, W1, b1, W2, b2,
                                                      (float*)d_out);
}